// Round 2
// baseline (2184.054 us; speedup 1.0000x reference)
//
#include <hip/hip_runtime.h>
#include <hip/hip_bf16.h>
#include <math.h>

#define DEPTH 6
#define DIM   768
#define HEADS 12
#define DH    64
#define NCTX  1024
#define BATCH 8
#define ROWS  (BATCH*NCTX)   /* 8192 */
#define DIM3  (3*DIM)        /* 2304 */
#define DIMF  (4*DIM)        /* 3072 */
#define LNEPS 1e-5f

typedef __attribute__((ext_vector_type(8))) short short8;
typedef __attribute__((ext_vector_type(4))) float floatx4;
using bf16 = __hip_bfloat16;

static __device__ __forceinline__ bf16 f2bf(float v){ return __float2bfloat16(v); }
static __device__ __forceinline__ float bf2f(unsigned short u){
    union { unsigned int i; float f; } c; c.i = ((unsigned int)u) << 16; return c.f;
}

// async global->LDS, 16B per lane; dst is wave-uniform base (readfirstlane) + lane*16
static __device__ __forceinline__ void gl_lds16(const void* g, void* l) {
    __builtin_amdgcn_global_load_lds((const __attribute__((address_space(1))) void*)g,
                                     (__attribute__((address_space(3))) void*)l, 16, 0, 0);
}

// ---------------------------------------------------------------------------
// W [L][K][N] fp32  ->  WT [L][N][K] bf16   (tiled transpose via LDS)
// ---------------------------------------------------------------------------
__global__ void k_transpose_convert(const float* __restrict__ W, bf16* __restrict__ WT,
                                    int K, int N) {
    __shared__ float tile[32][33];
    int l = blockIdx.z;
    const float* Wl = W + (size_t)l * K * N;
    bf16* WTl = WT + (size_t)l * K * N;
    int n0 = blockIdx.x * 32, k0 = blockIdx.y * 32;
    int tx = threadIdx.x, ty = threadIdx.y;
#pragma unroll
    for (int i = 0; i < 4; i++)
        tile[ty + i*8][tx] = Wl[(size_t)(k0 + ty + i*8) * N + n0 + tx];
    __syncthreads();
#pragma unroll
    for (int i = 0; i < 4; i++)
        WTl[(size_t)(n0 + ty + i*8) * K + k0 + tx] = f2bf(tile[tx][ty + i*8]);
}

// ---------------------------------------------------------------------------
// LayerNorm: x fp32 [ROWS][DIM] -> y bf16 [ROWS][DIM].  1 block / row.
// ---------------------------------------------------------------------------
__global__ __launch_bounds__(256) void k_layernorm(const float* __restrict__ x,
                                                   const float* __restrict__ g,
                                                   const float* __restrict__ b,
                                                   bf16* __restrict__ y) {
    int row = blockIdx.x;
    const float* xr = x + (size_t)row * DIM;
    int t = threadIdx.x;
    float v[3];
    float s = 0.f, s2 = 0.f;
#pragma unroll
    for (int i = 0; i < 3; i++) { v[i] = xr[t + i*256]; s += v[i]; s2 += v[i]*v[i]; }
#pragma unroll
    for (int m = 1; m < 64; m <<= 1) { s += __shfl_xor(s, m); s2 += __shfl_xor(s2, m); }
    __shared__ float ss[4], ss2[4];
    int w = t >> 6;
    if ((t & 63) == 0) { ss[w] = s; ss2[w] = s2; }
    __syncthreads();
    s  = ss[0] + ss[1] + ss[2] + ss[3];
    s2 = ss2[0] + ss2[1] + ss2[2] + ss2[3];
    float mu  = s * (1.f / DIM);
    float var = s2 * (1.f / DIM) - mu * mu;
    float rs  = rsqrtf(var + LNEPS);
    bf16* yr = y + (size_t)row * DIM;
#pragma unroll
    for (int i = 0; i < 3; i++) {
        int c = t + i*256;
        yr[c] = f2bf((v[i] - mu) * rs * g[c] + b[c]);
    }
}

// ---------------------------------------------------------------------------
// m97-structure GEMM: C[M][N] = act(A[M][K] @ WT[N][K]^T + bias)
// BM=BN=128, BK=32, 4 waves (2x2) of 64x64, global_load_lds width-16, linear LDS.
// MODE 0: bf16 store; MODE 1: bf16 GELU store; MODE 2: fp32 residual add.
// ---------------------------------------------------------------------------
template<int MODE>
__global__ __launch_bounds__(256) void k_gemm(const bf16* __restrict__ A,
                                              const bf16* __restrict__ WT,
                                              const float* __restrict__ bias,
                                              bf16* __restrict__ outb,
                                              float* __restrict__ outf,
                                              int N, int K) {
    __shared__ __align__(16) bf16 As[128*32];
    __shared__ __align__(16) bf16 Bs[128*32];
    int m0 = blockIdx.y * 128, n0 = blockIdx.x * 128;
    int t = threadIdx.x;
    int lane = t & 63, w = t >> 6;
    int wr = (w >> 1) * 64, wc = (w & 1) * 64;
    int lr = lane & 15, lg = lane >> 4;
    floatx4 acc[4][4] = {};
    for (int k0 = 0; k0 < K; k0 += 32) {
#pragma unroll
        for (int it = 0; it < 2; it++) {
            int c = it * 256 + t;              // 512 chunks of 16B per tile
            int row = c >> 2, colE = (c & 3) * 8;
            gl_lds16(&A [(size_t)(m0 + row) * K + k0 + colE], &As[c * 8]);
            gl_lds16(&WT[(size_t)(n0 + row) * K + k0 + colE], &Bs[c * 8]);
        }
        __syncthreads();
        short8 af[4], bfr[4];
#pragma unroll
        for (int i = 0; i < 4; i++) af[i]  = *(const short8*)&As[(wr + i*16 + lr)*32 + lg*8];
#pragma unroll
        for (int j = 0; j < 4; j++) bfr[j] = *(const short8*)&Bs[(wc + j*16 + lr)*32 + lg*8];
#pragma unroll
        for (int i = 0; i < 4; i++)
#pragma unroll
            for (int j = 0; j < 4; j++)
                acc[i][j] = __builtin_amdgcn_mfma_f32_16x16x32_bf16(af[i], bfr[j], acc[i][j], 0, 0, 0);
        __syncthreads();
    }
#pragma unroll
    for (int i = 0; i < 4; i++)
#pragma unroll
        for (int j = 0; j < 4; j++)
#pragma unroll
            for (int r = 0; r < 4; r++) {
                int row = m0 + wr + i*16 + lg*4 + r;
                int col = n0 + wc + j*16 + lr;
                float vv = acc[i][j][r] + bias[col];
                if (MODE == 0) {
                    outb[(size_t)row * N + col] = f2bf(vv);
                } else if (MODE == 1) {
                    outb[(size_t)row * N + col] = f2bf(0.5f * vv * (1.f + erff(vv * 0.70710678118f)));
                } else {
                    outf[(size_t)row * N + col] += vv;
                }
            }
}

// ---------------------------------------------------------------------------
// Flash attention, fused residual add into x (fp32).
// QBLK=64 (4 waves x 16 q-rows), KVBLK=64, grid 1536 blocks, XCD swizzle:
// batch b lives entirely on XCD b (K/V = 3.1 MB < 4 MB L2/XCD).
// Q pre-scaled by 768^-0.5 * log2(e); softmax in exp2 domain; defer-max THR=8.
// ---------------------------------------------------------------------------
__global__ __launch_bounds__(256) void k_attn(const bf16* __restrict__ qkv,
                                              float* __restrict__ x) {
    int f = blockIdx.x + (blockIdx.y << 4) + blockIdx.z * 192;  // grid (16,12,8)
    int b  = f & 7;
    int s2 = f >> 3;              // 0..191
    int h  = s2 % 12;
    int qt = s2 / 12;             // 0..15
    int t = threadIdx.x, lane = t & 63, w = t >> 6;
    int lr = lane & 15, lg = lane >> 4;
    const size_t bn0 = (size_t)b * NCTX;
    const bf16* Qg = qkv + bn0 * DIM3 + h * DH;
    const bf16* Kg = Qg + DIM;
    const bf16* Vg = Qg + 2 * DIM;
    int q0 = qt * 64 + w * 16;

    const float qs = 0.036084391824351615f * 1.4426950408889634f;  // 768^-0.5 * log2e
    short8 qf[2];
#pragma unroll
    for (int s = 0; s < 2; s++) {
        short8 raw = *(const short8*)&Qg[(size_t)(q0 + lr) * DIM3 + s*32 + lg*8];
        short8 o;
#pragma unroll
        for (int e = 0; e < 8; e++)
            o[e] = (short)__bfloat16_as_ushort(f2bf(bf2f((unsigned short)raw[e]) * qs));
        qf[s] = o;
    }

    __shared__ __align__(16) bf16 Ks[64][72];
    __shared__ __align__(16) bf16 VTs[64][72];
    __shared__ __align__(16) bf16 Ps[4][16][72];

    floatx4 oacc[4] = {};
    float mrow[4], lrow[4];
#pragma unroll
    for (int r = 0; r < 4; r++) { mrow[r] = -1e30f; lrow[r] = 0.f; }

    for (int kt = 0; kt < 16; kt++) {
        __syncthreads();
        int kv0 = kt * 64;
#pragma unroll
        for (int it = 0; it < 2; it++) {
            int c = it * 256 + t;              // 512 chunks: 64 rows x 8
            int row = c >> 3, col = (c & 7) * 8;
            *(uint4*)&Ks[row][col] = *(const uint4*)&Kg[(size_t)(kv0 + row) * DIM3 + col];
            uint4 vv = *(const uint4*)&Vg[(size_t)(kv0 + row) * DIM3 + col];
            const bf16* vp = (const bf16*)&vv;
#pragma unroll
            for (int e = 0; e < 8; e++) VTs[col + e][row] = vp[e];
        }
        __syncthreads();

        floatx4 sacc[4] = {};
#pragma unroll
        for (int j = 0; j < 4; j++) {
            short8 kf0 = *(const short8*)&Ks[j*16 + lr][lg*8];
            short8 kf1 = *(const short8*)&Ks[j*16 + lr][32 + lg*8];
            sacc[j] = __builtin_amdgcn_mfma_f32_16x16x32_bf16(qf[0], kf0, sacc[j], 0, 0, 0);
            sacc[j] = __builtin_amdgcn_mfma_f32_16x16x32_bf16(qf[1], kf1, sacc[j], 0, 0, 0);
        }

#pragma unroll
        for (int r = 0; r < 4; r++) {
            float mx = fmaxf(fmaxf(sacc[0][r], sacc[1][r]), fmaxf(sacc[2][r], sacc[3][r]));
#pragma unroll
            for (int m = 1; m < 16; m <<= 1) mx = fmaxf(mx, __shfl_xor(mx, m));
            if (mx > mrow[r] + 8.f) {          // defer-max: rescale only on real growth
                float corr = exp2f(mrow[r] - mx);
                mrow[r] = mx;
                lrow[r] *= corr;
#pragma unroll
                for (int j = 0; j < 4; j++) oacc[j][r] *= corr;
            }
            float sum = 0.f;
#pragma unroll
            for (int j = 0; j < 4; j++) {
                float pv = exp2f(sacc[j][r] - mrow[r]);
                sum += pv;
                Ps[w][lg*4 + r][j*16 + lr] = f2bf(pv);
            }
#pragma unroll
            for (int m = 1; m < 16; m <<= 1) sum += __shfl_xor(sum, m);
            lrow[r] += sum;
        }
        __syncthreads();

#pragma unroll
        for (int s = 0; s < 2; s++) {
            short8 pa = *(const short8*)&Ps[w][lr][s*32 + lg*8];
#pragma unroll
            for (int j = 0; j < 4; j++) {
                short8 vbf = *(const short8*)&VTs[j*16 + lr][s*32 + lg*8];
                oacc[j] = __builtin_amdgcn_mfma_f32_16x16x32_bf16(pa, vbf, oacc[j], 0, 0, 0);
            }
        }
    }

    float* xr = x + bn0 * DIM + (size_t)h * DH;
#pragma unroll
    for (int j = 0; j < 4; j++)
#pragma unroll
        for (int r = 0; r < 4; r++) {
            int row = q0 + lg*4 + r;
            int col = j*16 + lr;
            xr[(size_t)row * DIM + col] += oacc[j][r] / lrow[r];
        }
}

// ---------------------------------------------------------------------------
extern "C" void kernel_launch(void* const* d_in, const int* in_sizes, int n_in,
                              void* d_out, int out_size, void* d_ws, size_t ws_size,
                              hipStream_t stream) {
    const float* x_in  = (const float*)d_in[0];
    const float* ln1_g = (const float*)d_in[1];
    const float* ln1_b = (const float*)d_in[2];
    const float* wqkv  = (const float*)d_in[3];
    const float* bqkv  = (const float*)d_in[4];
    const float* ln2_g = (const float*)d_in[5];
    const float* ln2_b = (const float*)d_in[6];
    const float* w1    = (const float*)d_in[7];
    const float* b1    = (const float*)d_in[8];
    const float* w2    = (const float*)d_in[9];
    const float* b2    = (const float*)d_in[10];
    float* x = (float*)d_out;

    char* ws = (char*)d_ws;
    size_t off = 0;
    auto alloc = [&](size_t bytes) { void* p = ws + off; off += (bytes + 255) & ~255ull; return p; };
    bf16* wqkvT = (bf16*)alloc((size_t)DEPTH * DIM * DIM3 * 2);
    bf16* w1T   = (bf16*)alloc((size_t)DEPTH * DIM * DIMF * 2);
    bf16* w2T   = (bf16*)alloc((size_t)DEPTH * DIMF * DIM * 2);
    bf16* xn    = (bf16*)alloc((size_t)ROWS * DIM * 2);
    bf16* qkvh  = (bf16*)alloc((size_t)ROWS * DIMF * 2);  // shared: qkv (2304) / h (3072)
    if (off > ws_size) return;

    hipMemcpyAsync(x, x_in, (size_t)ROWS * DIM * 4, hipMemcpyDeviceToDevice, stream);

    k_transpose_convert<<<dim3(DIM3/32, DIM/32,  DEPTH), dim3(32, 8), 0, stream>>>(wqkv, wqkvT, DIM,  DIM3);
    k_transpose_convert<<<dim3(DIMF/32, DIM/32,  DEPTH), dim3(32, 8), 0, stream>>>(w1,   w1T,   DIM,  DIMF);
    k_transpose_convert<<<dim3(DIM/32,  DIMF/32, DEPTH), dim3(32, 8), 0, stream>>>(w2,   w2T,   DIMF, DIM);

    for (int l = 0; l < DEPTH; l++) {
        k_layernorm<<<ROWS, 256, 0, stream>>>(x, ln1_g + l*DIM, ln1_b + l*DIM, xn);
        k_gemm<0><<<dim3(DIM3/128, ROWS/128), 256, 0, stream>>>(
            xn, wqkvT + (size_t)l*DIM*DIM3, bqkv + (size_t)l*DIM3, qkvh, nullptr, DIM3, DIM);
        k_attn<<<dim3(16, HEADS, BATCH), 256, 0, stream>>>(qkvh, x);
        k_layernorm<<<ROWS, 256, 0, stream>>>(x, ln2_g + l*DIM, ln2_b + l*DIM, xn);
        k_gemm<1><<<dim3(DIMF/128, ROWS/128), 256, 0, stream>>>(
            xn, w1T + (size_t)l*DIM*DIMF, b1 + (size_t)l*DIMF, qkvh, nullptr, DIMF, DIM);
        k_gemm<2><<<dim3(DIM/128, ROWS/128), 256, 0, stream>>>(
            qkvh, w2T + (size_t)l*DIMF*DIM, b2 + (size_t)l*DIM, nullptr, x, DIM, DIMF);
    }
}

// Round 3
// 2051.260 us; speedup vs baseline: 1.0647x; 1.0647x over previous
//
#include <hip/hip_runtime.h>
#include <hip/hip_bf16.h>
#include <math.h>

#define DEPTH 6
#define DIM   768
#define HEADS 12
#define DH    64
#define NCTX  1024
#define BATCH 8
#define ROWS  (BATCH*NCTX)   /* 8192 */
#define DIM3  (3*DIM)        /* 2304 */
#define DIMF  (4*DIM)        /* 3072 */
#define LNEPS 1e-5f

typedef __attribute__((ext_vector_type(8))) short short8;
typedef __attribute__((ext_vector_type(4))) float floatx4;
using bf16 = __hip_bfloat16;

static __device__ __forceinline__ bf16 f2bf(float v){ return __float2bfloat16(v); }
static __device__ __forceinline__ float bf2f(unsigned short u){
    union { unsigned int i; float f; } c; c.i = ((unsigned int)u) << 16; return c.f;
}

// async global->LDS, 16B per lane
static __device__ __forceinline__ void gl_lds16(const void* g, void* l) {
    __builtin_amdgcn_global_load_lds((const __attribute__((address_space(1))) void*)g,
                                     (__attribute__((address_space(3))) void*)l, 16, 0, 0);
}

// ---------------------------------------------------------------------------
// W [L][K][N] fp32  ->  WT [L][N][K] bf16   (tiled transpose via LDS)
// ---------------------------------------------------------------------------
__global__ void k_transpose_convert(const float* __restrict__ W, bf16* __restrict__ WT,
                                    int K, int N) {
    __shared__ float tile[32][33];
    int l = blockIdx.z;
    const float* Wl = W + (size_t)l * K * N;
    bf16* WTl = WT + (size_t)l * K * N;
    int n0 = blockIdx.x * 32, k0 = blockIdx.y * 32;
    int tx = threadIdx.x, ty = threadIdx.y;
#pragma unroll
    for (int i = 0; i < 4; i++)
        tile[ty + i*8][tx] = Wl[(size_t)(k0 + ty + i*8) * N + n0 + tx];
    __syncthreads();
#pragma unroll
    for (int i = 0; i < 4; i++)
        WTl[(size_t)(n0 + ty + i*8) * K + k0 + tx] = f2bf(tile[tx][ty + i*8]);
}

// ---------------------------------------------------------------------------
// LayerNorm: x fp32 [ROWS][DIM] -> y bf16 [ROWS][DIM].  1 block / row.
// ---------------------------------------------------------------------------
__global__ __launch_bounds__(256) void k_layernorm(const float* __restrict__ x,
                                                   const float* __restrict__ g,
                                                   const float* __restrict__ b,
                                                   bf16* __restrict__ y) {
    int row = blockIdx.x;
    const float* xr = x + (size_t)row * DIM;
    int t = threadIdx.x;
    float v[3];
    float s = 0.f, s2 = 0.f;
#pragma unroll
    for (int i = 0; i < 3; i++) { v[i] = xr[t + i*256]; s += v[i]; s2 += v[i]*v[i]; }
#pragma unroll
    for (int m = 1; m < 64; m <<= 1) { s += __shfl_xor(s, m); s2 += __shfl_xor(s2, m); }
    __shared__ float ss[4], ss2[4];
    int w = t >> 6;
    if ((t & 63) == 0) { ss[w] = s; ss2[w] = s2; }
    __syncthreads();
    s  = ss[0] + ss[1] + ss[2] + ss[3];
    s2 = ss2[0] + ss2[1] + ss2[2] + ss2[3];
    float mu  = s * (1.f / DIM);
    float var = s2 * (1.f / DIM) - mu * mu;
    float rs  = rsqrtf(var + LNEPS);
    bf16* yr = y + (size_t)row * DIM;
#pragma unroll
    for (int i = 0; i < 3; i++) {
        int c = t + i*256;
        yr[c] = f2bf((v[i] - mu) * rs * g[c] + b[c]);
    }
}

// ---------------------------------------------------------------------------
// m97-structure GEMM with XCD chunk swizzle (m-major chunks per XCD).
// C[M][N] = act(A[M][K] @ WT[N][K]^T + bias), BM=BN=128, BK=32, 4 waves 2x2.
// MODE 0: bf16 store; MODE 1: bf16 GELU store; MODE 2: fp32 residual add.
// nwg must be divisible by 8.
// ---------------------------------------------------------------------------
template<int MODE>
__global__ __launch_bounds__(256) void k_gemm(const bf16* __restrict__ A,
                                              const bf16* __restrict__ WT,
                                              const float* __restrict__ bias,
                                              bf16* __restrict__ outb,
                                              float* __restrict__ outf,
                                              int N, int K) {
    __shared__ __align__(16) bf16 As[128*32];
    __shared__ __align__(16) bf16 Bs[128*32];
    int nt = N >> 7;
    int nwg = gridDim.x;
    int fblk = blockIdx.x;
    int swz = (fblk & 7) * (nwg >> 3) + (fblk >> 3);  // XCD-chunked, bijective (nwg%8==0)
    int m0 = (swz / nt) * 128, n0 = (swz % nt) * 128;
    int t = threadIdx.x;
    int lane = t & 63, w = t >> 6;
    int wr = (w >> 1) * 64, wc = (w & 1) * 64;
    int lr = lane & 15, lg = lane >> 4;
    floatx4 acc[4][4] = {};
    for (int k0 = 0; k0 < K; k0 += 32) {
#pragma unroll
        for (int it = 0; it < 2; it++) {
            int c = it * 256 + t;              // 512 chunks of 16B per tile
            int row = c >> 2, colE = (c & 3) * 8;
            gl_lds16(&A [(size_t)(m0 + row) * K + k0 + colE], &As[c * 8]);
            gl_lds16(&WT[(size_t)(n0 + row) * K + k0 + colE], &Bs[c * 8]);
        }
        __syncthreads();
        short8 af[4], bfr[4];
#pragma unroll
        for (int i = 0; i < 4; i++) af[i]  = *(const short8*)&As[(wr + i*16 + lr)*32 + lg*8];
#pragma unroll
        for (int j = 0; j < 4; j++) bfr[j] = *(const short8*)&Bs[(wc + j*16 + lr)*32 + lg*8];
#pragma unroll
        for (int i = 0; i < 4; i++)
#pragma unroll
            for (int j = 0; j < 4; j++)
                acc[i][j] = __builtin_amdgcn_mfma_f32_16x16x32_bf16(af[i], bfr[j], acc[i][j], 0, 0, 0);
        __syncthreads();
    }
#pragma unroll
    for (int i = 0; i < 4; i++)
#pragma unroll
        for (int j = 0; j < 4; j++)
#pragma unroll
            for (int r = 0; r < 4; r++) {
                int row = m0 + wr + i*16 + lg*4 + r;
                int col = n0 + wc + j*16 + lr;
                float vv = acc[i][j][r] + bias[col];
                if (MODE == 0) {
                    outb[(size_t)row * N + col] = f2bf(vv);
                } else if (MODE == 1) {
                    outb[(size_t)row * N + col] = f2bf(0.5f * vv * (1.f + erff(vv * 0.70710678118f)));
                } else {
                    outf[(size_t)row * N + col] += vv;
                }
            }
}

// ---------------------------------------------------------------------------
// Flash attention, fused residual add into x (fp32).
// QBLK=128 (4 waves x 32 rows), KVBLK=64, grid 768 (1-D): b = f&7 -> XCD = batch
// (K/V per batch = 3.1 MB, L2-resident).  Q pre-scaled by 768^-0.5*log2e;
// exp2-domain online softmax, defer-max THR=8.
// V^T in LDS with dword-XOR swizzle: phys_dw = (d*36 + (k>>1)) ^ ((d&0x38)>>1)
//   -> transpose scalar writes drop 16-way -> 2-way; b128 reads stay 2-way,
//      16B-aligned and contiguous (k0>>1 % 4 == 0, XOR bits 2-4 only).
// ---------------------------------------------------------------------------
static __device__ __forceinline__ int vt_off(int d, int k) {
    int dw = d * 36 + (k >> 1);
    dw ^= (d & 0x38) >> 1;        // ((d>>3)&7)<<2
    return dw * 2 + (k & 1);
}

__global__ __launch_bounds__(256) void k_attn(const bf16* __restrict__ qkv,
                                              float* __restrict__ x) {
    int f = blockIdx.x;           // 768 blocks; XCD = f % 8 (empirical round-robin)
    int b  = f & 7;
    int rr = f >> 3;              // 0..95
    int h  = rr % 12;
    int qt = rr / 12;             // 0..7
    int t = threadIdx.x, lane = t & 63, w = t >> 6;
    int lr = lane & 15, lg = lane >> 4;
    const size_t bn0 = (size_t)b * NCTX;
    const bf16* Qg = qkv + bn0 * DIM3 + h * DH;
    const bf16* Kg = Qg + DIM;
    const bf16* Vg = Qg + 2 * DIM;
    int q0 = qt * 128 + w * 32;

    const float qs = 0.036084391824351615f * 1.4426950408889634f;  // 768^-0.5 * log2e
    short8 qf[2][2];
#pragma unroll
    for (int i = 0; i < 2; i++)
#pragma unroll
        for (int s = 0; s < 2; s++) {
            short8 raw = *(const short8*)&Qg[(size_t)(q0 + i*16 + lr) * DIM3 + s*32 + lg*8];
            short8 o;
#pragma unroll
            for (int e = 0; e < 8; e++)
                o[e] = (short)__bfloat16_as_ushort(f2bf(bf2f((unsigned short)raw[e]) * qs));
            qf[i][s] = o;
        }

    __shared__ __align__(16) bf16 Ks[64][72];
    __shared__ __align__(16) bf16 VTs[64 * 72];   // XOR-swizzled, [d][k] logical
    __shared__ __align__(16) bf16 Ps[4][32][72];

    floatx4 oacc[2][4] = {};
    float mrow[2][4], lrow[2][4];
#pragma unroll
    for (int i = 0; i < 2; i++)
#pragma unroll
        for (int r = 0; r < 4; r++) { mrow[i][r] = -1e30f; lrow[i][r] = 0.f; }

    for (int kt = 0; kt < 16; kt++) {
        __syncthreads();          // protect Ks/VTs from previous tile's readers
        int kv0 = kt * 64;
#pragma unroll
        for (int it = 0; it < 2; it++) {
            int c = it * 256 + t;              // 512 chunks: 64 rows x 8
            int row = c >> 3, col = (c & 7) * 8;
            *(uint4*)&Ks[row][col] = *(const uint4*)&Kg[(size_t)(kv0 + row) * DIM3 + col];
            uint4 vv = *(const uint4*)&Vg[(size_t)(kv0 + row) * DIM3 + col];
            const bf16* vp = (const bf16*)&vv;
#pragma unroll
            for (int e = 0; e < 8; e++) VTs[vt_off(col + e, row)] = vp[e];
        }
        __syncthreads();

        floatx4 sacc[2][4] = {};
#pragma unroll
        for (int j = 0; j < 4; j++) {
            short8 kf0 = *(const short8*)&Ks[j*16 + lr][lg*8];
            short8 kf1 = *(const short8*)&Ks[j*16 + lr][32 + lg*8];
#pragma unroll
            for (int i = 0; i < 2; i++) {
                sacc[i][j] = __builtin_amdgcn_mfma_f32_16x16x32_bf16(qf[i][0], kf0, sacc[i][j], 0, 0, 0);
                sacc[i][j] = __builtin_amdgcn_mfma_f32_16x16x32_bf16(qf[i][1], kf1, sacc[i][j], 0, 0, 0);
            }
        }

#pragma unroll
        for (int i = 0; i < 2; i++)
#pragma unroll
            for (int r = 0; r < 4; r++) {
                float mx = fmaxf(fmaxf(sacc[i][0][r], sacc[i][1][r]),
                                 fmaxf(sacc[i][2][r], sacc[i][3][r]));
#pragma unroll
                for (int m = 1; m < 16; m <<= 1) mx = fmaxf(mx, __shfl_xor(mx, m));
                if (mx > mrow[i][r] + 8.f) {   // defer-max
                    float corr = exp2f(mrow[i][r] - mx);
                    mrow[i][r] = mx;
                    lrow[i][r] *= corr;
#pragma unroll
                    for (int j = 0; j < 4; j++) oacc[i][j][r] *= corr;
                }
                float sum = 0.f;
#pragma unroll
                for (int j = 0; j < 4; j++) {
                    float pv = exp2f(sacc[i][j][r] - mrow[i][r]);
                    sum += pv;
                    Ps[w][i*16 + lg*4 + r][j*16 + lr] = f2bf(pv);
                }
#pragma unroll
                for (int m = 1; m < 16; m <<= 1) sum += __shfl_xor(sum, m);
                lrow[i][r] += sum;
            }
        // no barrier: Ps is per-wave (lgkmcnt ordering suffices); VTs/Ks stable

#pragma unroll
        for (int s = 0; s < 2; s++) {
            short8 pa[2];
#pragma unroll
            for (int i = 0; i < 2; i++) pa[i] = *(const short8*)&Ps[w][i*16 + lr][s*32 + lg*8];
#pragma unroll
            for (int j = 0; j < 4; j++) {
                short8 vb = *(const short8*)&VTs[vt_off(j*16 + lr, s*32 + lg*8)];
#pragma unroll
                for (int i = 0; i < 2; i++)
                    oacc[i][j] = __builtin_amdgcn_mfma_f32_16x16x32_bf16(pa[i], vb, oacc[i][j], 0, 0, 0);
            }
        }
    }

    float* xr = x + bn0 * DIM + (size_t)h * DH;
#pragma unroll
    for (int i = 0; i < 2; i++)
#pragma unroll
        for (int j = 0; j < 4; j++)
#pragma unroll
            for (int r = 0; r < 4; r++) {
                int row = q0 + i*16 + lg*4 + r;
                int col = j*16 + lr;
                xr[(size_t)row * DIM + col] += oacc[i][j][r] / lrow[i][r];
            }
}

// ---------------------------------------------------------------------------
extern "C" void kernel_launch(void* const* d_in, const int* in_sizes, int n_in,
                              void* d_out, int out_size, void* d_ws, size_t ws_size,
                              hipStream_t stream) {
    const float* x_in  = (const float*)d_in[0];
    const float* ln1_g = (const float*)d_in[1];
    const float* ln1_b = (const float*)d_in[2];
    const float* wqkv  = (const float*)d_in[3];
    const float* bqkv  = (const float*)d_in[4];
    const float* ln2_g = (const float*)d_in[5];
    const float* ln2_b = (const float*)d_in[6];
    const float* w1    = (const float*)d_in[7];
    const float* b1    = (const float*)d_in[8];
    const float* w2    = (const float*)d_in[9];
    const float* b2    = (const float*)d_in[10];
    float* x = (float*)d_out;

    char* ws = (char*)d_ws;
    size_t off = 0;
    auto alloc = [&](size_t bytes) { void* p = ws + off; off += (bytes + 255) & ~255ull; return p; };
    bf16* wqkvT = (bf16*)alloc((size_t)DEPTH * DIM * DIM3 * 2);
    bf16* w1T   = (bf16*)alloc((size_t)DEPTH * DIM * DIMF * 2);
    bf16* w2T   = (bf16*)alloc((size_t)DEPTH * DIMF * DIM * 2);
    bf16* xn    = (bf16*)alloc((size_t)ROWS * DIM * 2);
    bf16* qkvh  = (bf16*)alloc((size_t)ROWS * DIMF * 2);  // shared: qkv (2304) / h (3072)
    if (off > ws_size) return;

    hipMemcpyAsync(x, x_in, (size_t)ROWS * DIM * 4, hipMemcpyDeviceToDevice, stream);

    k_transpose_convert<<<dim3(DIM3/32, DIM/32,  DEPTH), dim3(32, 8), 0, stream>>>(wqkv, wqkvT, DIM,  DIM3);
    k_transpose_convert<<<dim3(DIMF/32, DIM/32,  DEPTH), dim3(32, 8), 0, stream>>>(w1,   w1T,   DIM,  DIMF);
    k_transpose_convert<<<dim3(DIM/32,  DIMF/32, DEPTH), dim3(32, 8), 0, stream>>>(w2,   w2T,   DIMF, DIM);

    for (int l = 0; l < DEPTH; l++) {
        k_layernorm<<<ROWS, 256, 0, stream>>>(x, ln1_g + l*DIM, ln1_b + l*DIM, xn);
        k_gemm<0><<<dim3((DIM3/128)*(ROWS/128)), 256, 0, stream>>>(
            xn, wqkvT + (size_t)l*DIM*DIM3, bqkv + (size_t)l*DIM3, qkvh, nullptr, DIM3, DIM);
        k_attn<<<dim3(768), 256, 0, stream>>>(qkvh, x);
        k_layernorm<<<ROWS, 256, 0, stream>>>(x, ln2_g + l*DIM, ln2_b + l*DIM, xn);
        k_gemm<1><<<dim3((DIMF/128)*(ROWS/128)), 256, 0, stream>>>(
            xn, w1T + (size_t)l*DIM*DIMF, b1 + (size_t)l*DIMF, qkvh, nullptr, DIMF, DIM);
        k_gemm<2><<<dim3((DIM/128)*(ROWS/128)), 256, 0, stream>>>(
            qkvh, w2T + (size_t)l*DIMF*DIM, b2 + (size_t)l*DIM, nullptr, x, DIM, DIMF);
    }
}

// Round 4
// 1784.898 us; speedup vs baseline: 1.2236x; 1.1492x over previous
//
#include <hip/hip_runtime.h>
#include <hip/hip_bf16.h>
#include <math.h>

#define DEPTH 6
#define DIM   768
#define HEADS 12
#define DH    64
#define NCTX  1024
#define BATCH 8
#define ROWS  (BATCH*NCTX)   /* 8192 */
#define DIM3  (3*DIM)        /* 2304 */
#define DIMF  (4*DIM)        /* 3072 */
#define LNEPS 1e-5f

typedef __attribute__((ext_vector_type(8))) short short8;
typedef __attribute__((ext_vector_type(4))) float floatx4;
using bf16 = __hip_bfloat16;

static __device__ __forceinline__ bf16 f2bf(float v){ return __float2bfloat16(v); }
static __device__ __forceinline__ float bf2f(unsigned short u){
    union { unsigned int i; float f; } c; c.i = ((unsigned int)u) << 16; return c.f;
}
static __device__ __forceinline__ unsigned short bfu(float v){ return __bfloat16_as_ushort(f2bf(v)); }

// async global->LDS, 16B per lane
static __device__ __forceinline__ void gl_lds16(const void* g, void* l) {
    __builtin_amdgcn_global_load_lds((const __attribute__((address_space(1))) void*)g,
                                     (__attribute__((address_space(3))) void*)l, 16, 0, 0);
}

// ---------------------------------------------------------------------------
// W [L][K][N] fp32  ->  WT [L][N][K] bf16   (tiled transpose via LDS)
// ---------------------------------------------------------------------------
__global__ void k_transpose_convert(const float* __restrict__ W, bf16* __restrict__ WT,
                                    int K, int N) {
    __shared__ float tile[32][33];
    int l = blockIdx.z;
    const float* Wl = W + (size_t)l * K * N;
    bf16* WTl = WT + (size_t)l * K * N;
    int n0 = blockIdx.x * 32, k0 = blockIdx.y * 32;
    int tx = threadIdx.x, ty = threadIdx.y;
#pragma unroll
    for (int i = 0; i < 4; i++)
        tile[ty + i*8][tx] = Wl[(size_t)(k0 + ty + i*8) * N + n0 + tx];
    __syncthreads();
#pragma unroll
    for (int i = 0; i < 4; i++)
        WTl[(size_t)(n0 + ty + i*8) * K + k0 + tx] = f2bf(tile[tx][ty + i*8]);
}

// ---------------------------------------------------------------------------
// LayerNorm: x fp32 [ROWS][DIM] -> y bf16.  One wave per row, float4 loads,
// wave-only shuffle reduce (no barrier).  grid ROWS/4, block 256.
// ---------------------------------------------------------------------------
__global__ __launch_bounds__(256) void k_layernorm(const float* __restrict__ x,
                                                   const float* __restrict__ g,
                                                   const float* __restrict__ b,
                                                   bf16* __restrict__ y) {
    int row  = blockIdx.x * 4 + (threadIdx.x >> 6);
    int lane = threadIdx.x & 63;
    const float4* xr = (const float4*)(x + (size_t)row * DIM);
    float4 v[3];
    float s = 0.f, s2 = 0.f;
#pragma unroll
    for (int i = 0; i < 3; i++) {
        v[i] = xr[lane + i*64];
        s  += v[i].x + v[i].y + v[i].z + v[i].w;
        s2 += v[i].x*v[i].x + v[i].y*v[i].y + v[i].z*v[i].z + v[i].w*v[i].w;
    }
#pragma unroll
    for (int m = 1; m < 64; m <<= 1) { s += __shfl_xor(s, m); s2 += __shfl_xor(s2, m); }
    float mu  = s * (1.f / DIM);
    float var = s2 * (1.f / DIM) - mu * mu;
    float rs  = rsqrtf(var + LNEPS);
    bf16* yr = y + (size_t)row * DIM;
    const float4* g4 = (const float4*)g;
    const float4* b4 = (const float4*)b;
#pragma unroll
    for (int i = 0; i < 3; i++) {
        float4 gg = g4[lane + i*64], bb = b4[lane + i*64];
        float r0 = (v[i].x - mu) * rs * gg.x + bb.x;
        float r1 = (v[i].y - mu) * rs * gg.y + bb.y;
        float r2 = (v[i].z - mu) * rs * gg.z + bb.z;
        float r3 = (v[i].w - mu) * rs * gg.w + bb.w;
        unsigned int lo = bfu(r0) | ((unsigned int)bfu(r1) << 16);
        unsigned int hi = bfu(r2) | ((unsigned int)bfu(r3) << 16);
        uint2 u; u.x = lo; u.y = hi;
        *(uint2*)&yr[4 * (lane + i*64)] = u;
    }
}

// ---------------------------------------------------------------------------
// 2-phase double-buffered GEMM (T3-minimum): STAGE(next) -> compute(cur) ->
// vmcnt(0)+barrier.  BM=BN=128, BK=32, 4 waves 2x2, gl_lds width-16, XCD swizzle.
// MODE 0: bf16 store; MODE 1: bf16 fast-GELU store; MODE 2: fp32 residual add.
// ---------------------------------------------------------------------------
template<int MODE>
__global__ __launch_bounds__(256) void k_gemm(const bf16* __restrict__ A,
                                              const bf16* __restrict__ WT,
                                              const float* __restrict__ bias,
                                              bf16* __restrict__ outb,
                                              float* __restrict__ outf,
                                              int N, int K) {
    __shared__ __align__(16) bf16 As[2][128*32];
    __shared__ __align__(16) bf16 Bs[2][128*32];
    int nt = N >> 7;
    int nwg = gridDim.x;
    int fblk = blockIdx.x;
    int swz = (fblk & 7) * (nwg >> 3) + (fblk >> 3);  // XCD-chunked, bijective (nwg%8==0)
    int m0 = (swz / nt) * 128, n0 = (swz % nt) * 128;
    int t = threadIdx.x;
    int lane = t & 63, w = t >> 6;
    int wr = (w >> 1) * 64, wc = (w & 1) * 64;
    int lr = lane & 15, lg = lane >> 4;
    // per-thread staging geometry (constant)
    int c0 = t, c1 = 256 + t;
    int r0g = c0 >> 2, e0 = (c0 & 3) * 8;
    int r1g = c1 >> 2, e1 = (c1 & 3) * 8;
    const bf16* Arow0 = A  + (size_t)(m0 + r0g) * K + e0;
    const bf16* Arow1 = A  + (size_t)(m0 + r1g) * K + e1;
    const bf16* Brow0 = WT + (size_t)(n0 + r0g) * K + e0;
    const bf16* Brow1 = WT + (size_t)(n0 + r1g) * K + e1;

    floatx4 acc[4][4] = {};
    int NT = K >> 5;
    // prologue: stage tile 0 into buf 0
    gl_lds16(Arow0, &As[0][c0 * 8]);
    gl_lds16(Brow0, &Bs[0][c0 * 8]);
    gl_lds16(Arow1, &As[0][c1 * 8]);
    gl_lds16(Brow1, &Bs[0][c1 * 8]);
    __syncthreads();
    int cur = 0;
    for (int ks = 0; ks < NT; ks++) {
        if (ks + 1 < NT) {                       // prefetch next tile (flies under MFMA)
            int ko = (ks + 1) << 5;
            gl_lds16(Arow0 + ko, &As[cur^1][c0 * 8]);
            gl_lds16(Brow0 + ko, &Bs[cur^1][c0 * 8]);
            gl_lds16(Arow1 + ko, &As[cur^1][c1 * 8]);
            gl_lds16(Brow1 + ko, &Bs[cur^1][c1 * 8]);
        }
        short8 af[4], bfr[4];
#pragma unroll
        for (int i = 0; i < 4; i++) af[i]  = *(const short8*)&As[cur][(wr + i*16 + lr)*32 + lg*8];
#pragma unroll
        for (int j = 0; j < 4; j++) bfr[j] = *(const short8*)&Bs[cur][(wc + j*16 + lr)*32 + lg*8];
#pragma unroll
        for (int i = 0; i < 4; i++)
#pragma unroll
            for (int j = 0; j < 4; j++)
                acc[i][j] = __builtin_amdgcn_mfma_f32_16x16x32_bf16(af[i], bfr[j], acc[i][j], 0, 0, 0);
        __syncthreads();                          // vmcnt(0)+barrier: next tile ready
        cur ^= 1;
    }
#pragma unroll
    for (int i = 0; i < 4; i++)
#pragma unroll
        for (int j = 0; j < 4; j++)
#pragma unroll
            for (int r = 0; r < 4; r++) {
                int row = m0 + wr + i*16 + lg*4 + r;
                int col = n0 + wc + j*16 + lr;
                float vv = acc[i][j][r] + bias[col];
                if (MODE == 0) {
                    outb[(size_t)row * N + col] = f2bf(vv);
                } else if (MODE == 1) {
                    // fast GELU: v * sigmoid(1.5957691216*(v + 0.044715 v^3))
                    float u = 1.5957691216f * (vv + 0.044715f * vv * vv * vv);
                    float gs = 1.f / (1.f + __expf(-u));
                    outb[(size_t)row * N + col] = f2bf(vv * gs);
                } else {
                    outf[(size_t)row * N + col] += vv;
                }
            }
}

// ---------------------------------------------------------------------------
// Flash attention, fused residual add into x (fp32).
// QBLK=128 (4 waves x 32 rows), KVBLK=64, grid 768: XCD = batch (K/V 3.1 MB, L2-res).
// T14 async staging: issue K/V global loads for tile kt+1 right before compute
// of tile kt; LDS write happens after the next loop-top barrier.
// V^T LDS uses dword-XOR swizzle (writes 2-way, b128 reads 2-way).
// ---------------------------------------------------------------------------
static __device__ __forceinline__ int vt_off(int d, int k) {
    int dw = d * 36 + (k >> 1);
    dw ^= (d & 0x38) >> 1;
    return dw * 2 + (k & 1);
}

__global__ __launch_bounds__(256, 3) void k_attn(const bf16* __restrict__ qkv,
                                                 float* __restrict__ x) {
    int f = blockIdx.x;           // 768 blocks; XCD = f % 8
    int b  = f & 7;
    int rr = f >> 3;
    int h  = rr % 12;
    int qt = rr / 12;
    int t = threadIdx.x, lane = t & 63, w = t >> 6;
    int lr = lane & 15, lg = lane >> 4;
    const size_t bn0 = (size_t)b * NCTX;
    const bf16* Qg = qkv + bn0 * DIM3 + h * DH;
    const bf16* Kg = Qg + DIM;
    const bf16* Vg = Qg + 2 * DIM;
    int q0 = qt * 128 + w * 32;

    const float qs = 0.036084391824351615f * 1.4426950408889634f;  // 768^-0.5 * log2e
    short8 qf[2][2];
#pragma unroll
    for (int i = 0; i < 2; i++)
#pragma unroll
        for (int s = 0; s < 2; s++) {
            short8 raw = *(const short8*)&Qg[(size_t)(q0 + i*16 + lr) * DIM3 + s*32 + lg*8];
            short8 o;
#pragma unroll
            for (int e = 0; e < 8; e++)
                o[e] = (short)bfu(bf2f((unsigned short)raw[e]) * qs);
            qf[i][s] = o;
        }

    __shared__ __align__(16) bf16 Ks[64][72];
    __shared__ __align__(16) bf16 VTs[64 * 72];   // XOR-swizzled [d][k]
    __shared__ __align__(16) bf16 Ps[4][32][72];

    // staging geometry (constant per thread): 2 chunks of 16B
    int sr[2], sc[2];
#pragma unroll
    for (int it = 0; it < 2; it++) { int c = it*256 + t; sr[it] = c >> 3; sc[it] = (c & 7) * 8; }

    floatx4 oacc[2][4] = {};
    float mrow[2][4], lrow[2][4];
#pragma unroll
    for (int i = 0; i < 2; i++)
#pragma unroll
        for (int r = 0; r < 4; r++) { mrow[i][r] = -1e30f; lrow[i][r] = 0.f; }

    uint4 kreg[2], vreg[2];
#pragma unroll
    for (int it = 0; it < 2; it++) {
        kreg[it] = *(const uint4*)&Kg[(size_t)sr[it] * DIM3 + sc[it]];
        vreg[it] = *(const uint4*)&Vg[(size_t)sr[it] * DIM3 + sc[it]];
    }

    for (int kt = 0; kt < 16; kt++) {
        __syncthreads();          // all waves done reading previous tile's LDS
#pragma unroll
        for (int it = 0; it < 2; it++) {
            *(uint4*)&Ks[sr[it]][sc[it]] = kreg[it];
            const bf16* vp = (const bf16*)&vreg[it];
#pragma unroll
            for (int e = 0; e < 8; e++) VTs[vt_off(sc[it] + e, sr[it])] = vp[e];
        }
        __syncthreads();
        if (kt + 1 < 16) {        // T14: issue next-tile loads; fly under compute
            int kv0 = (kt + 1) * 64;
#pragma unroll
            for (int it = 0; it < 2; it++) {
                kreg[it] = *(const uint4*)&Kg[(size_t)(kv0 + sr[it]) * DIM3 + sc[it]];
                vreg[it] = *(const uint4*)&Vg[(size_t)(kv0 + sr[it]) * DIM3 + sc[it]];
            }
        }

        floatx4 sacc[2][4] = {};
#pragma unroll
        for (int j = 0; j < 4; j++) {
            short8 kf0 = *(const short8*)&Ks[j*16 + lr][lg*8];
            short8 kf1 = *(const short8*)&Ks[j*16 + lr][32 + lg*8];
#pragma unroll
            for (int i = 0; i < 2; i++) {
                sacc[i][j] = __builtin_amdgcn_mfma_f32_16x16x32_bf16(qf[i][0], kf0, sacc[i][j], 0, 0, 0);
                sacc[i][j] = __builtin_amdgcn_mfma_f32_16x16x32_bf16(qf[i][1], kf1, sacc[i][j], 0, 0, 0);
            }
        }

#pragma unroll
        for (int i = 0; i < 2; i++)
#pragma unroll
            for (int r = 0; r < 4; r++) {
                float mx = fmaxf(fmaxf(sacc[i][0][r], sacc[i][1][r]),
                                 fmaxf(sacc[i][2][r], sacc[i][3][r]));
#pragma unroll
                for (int m = 1; m < 16; m <<= 1) mx = fmaxf(mx, __shfl_xor(mx, m));
                if (mx > mrow[i][r] + 8.f) {   // defer-max
                    float corr = exp2f(mrow[i][r] - mx);
                    mrow[i][r] = mx;
                    lrow[i][r] *= corr;
#pragma unroll
                    for (int j = 0; j < 4; j++) oacc[i][j][r] *= corr;
                }
                float sum = 0.f;
#pragma unroll
                for (int j = 0; j < 4; j++) {
                    float pv = exp2f(sacc[i][j][r] - mrow[i][r]);
                    sum += pv;
                    Ps[w][i*16 + lg*4 + r][j*16 + lr] = f2bf(pv);
                }
#pragma unroll
                for (int m = 1; m < 16; m <<= 1) sum += __shfl_xor(sum, m);
                lrow[i][r] += sum;
            }
        // no barrier: Ps is per-wave

#pragma unroll
        for (int s = 0; s < 2; s++) {
            short8 pa[2];
#pragma unroll
            for (int i = 0; i < 2; i++) pa[i] = *(const short8*)&Ps[w][i*16 + lr][s*32 + lg*8];
#pragma unroll
            for (int j = 0; j < 4; j++) {
                short8 vb = *(const short8*)&VTs[vt_off(j*16 + lr, s*32 + lg*8)];
#pragma unroll
                for (int i = 0; i < 2; i++)
                    oacc[i][j] = __builtin_amdgcn_mfma_f32_16x16x32_bf16(pa[i], vb, oacc[i][j], 0, 0, 0);
            }
        }
    }

    float* xr = x + bn0 * DIM + (size_t)h * DH;
#pragma unroll
    for (int i = 0; i < 2; i++)
#pragma unroll
        for (int j = 0; j < 4; j++)
#pragma unroll
            for (int r = 0; r < 4; r++) {
                int row = q0 + i*16 + lg*4 + r;
                int col = j*16 + lr;
                xr[(size_t)row * DIM + col] += oacc[i][j][r] / lrow[i][r];
            }
}

// ---------------------------------------------------------------------------
extern "C" void kernel_launch(void* const* d_in, const int* in_sizes, int n_in,
                              void* d_out, int out_size, void* d_ws, size_t ws_size,
                              hipStream_t stream) {
    const float* x_in  = (const float*)d_in[0];
    const float* ln1_g = (const float*)d_in[1];
    const float* ln1_b = (const float*)d_in[2];
    const float* wqkv  = (const float*)d_in[3];
    const float* bqkv  = (const float*)d_in[4];
    const float* ln2_g = (const float*)d_in[5];
    const float* ln2_b = (const float*)d_in[6];
    const float* w1    = (const float*)d_in[7];
    const float* b1    = (const float*)d_in[8];
    const float* w2    = (const float*)d_in[9];
    const float* b2    = (const float*)d_in[10];
    float* x = (float*)d_out;

    char* ws = (char*)d_ws;
    size_t off = 0;
    auto alloc = [&](size_t bytes) { void* p = ws + off; off += (bytes + 255) & ~255ull; return p; };
    bf16* wqkvT = (bf16*)alloc((size_t)DEPTH * DIM * DIM3 * 2);
    bf16* w1T   = (bf16*)alloc((size_t)DEPTH * DIM * DIMF * 2);
    bf16* w2T   = (bf16*)alloc((size_t)DEPTH * DIMF * DIM * 2);
    bf16* xn    = (bf16*)alloc((size_t)ROWS * DIM * 2);
    bf16* qkvh  = (bf16*)alloc((size_t)ROWS * DIMF * 2);  // shared: qkv (2304) / h (3072)
    if (off > ws_size) return;

    hipMemcpyAsync(x, x_in, (size_t)ROWS * DIM * 4, hipMemcpyDeviceToDevice, stream);

    k_transpose_convert<<<dim3(DIM3/32, DIM/32,  DEPTH), dim3(32, 8), 0, stream>>>(wqkv, wqkvT, DIM,  DIM3);
    k_transpose_convert<<<dim3(DIMF/32, DIM/32,  DEPTH), dim3(32, 8), 0, stream>>>(w1,   w1T,   DIM,  DIMF);
    k_transpose_convert<<<dim3(DIM/32,  DIMF/32, DEPTH), dim3(32, 8), 0, stream>>>(w2,   w2T,   DIMF, DIM);

    for (int l = 0; l < DEPTH; l++) {
        k_layernorm<<<ROWS/4, 256, 0, stream>>>(x, ln1_g + l*DIM, ln1_b + l*DIM, xn);
        k_gemm<0><<<dim3((DIM3/128)*(ROWS/128)), 256, 0, stream>>>(
            xn, wqkvT + (size_t)l*DIM*DIM3, bqkv + (size_t)l*DIM3, qkvh, nullptr, DIM3, DIM);
        k_attn<<<dim3(768), 256, 0, stream>>>(qkvh, x);
        k_layernorm<<<ROWS/4, 256, 0, stream>>>(x, ln2_g + l*DIM, ln2_b + l*DIM, xn);
        k_gemm<1><<<dim3((DIMF/128)*(ROWS/128)), 256, 0, stream>>>(
            xn, w1T + (size_t)l*DIM*DIMF, b1 + (size_t)l*DIMF, qkvh, nullptr, DIMF, DIM);
        k_gemm<2><<<dim3((DIM/128)*(ROWS/128)), 256, 0, stream>>>(
            qkvh, w2T + (size_t)l*DIMF*DIM, b2 + (size_t)l*DIM, nullptr, x, DIM, DIMF);
    }
}

// Round 5
// 1648.253 us; speedup vs baseline: 1.3251x; 1.0829x over previous
//
#include <hip/hip_runtime.h>
#include <hip/hip_bf16.h>
#include <math.h>

#define DEPTH 6
#define DIM   768
#define HEADS 12
#define DH    64
#define NCTX  1024
#define BATCH 8
#define ROWS  (BATCH*NCTX)   /* 8192 */
#define DIM3  (3*DIM)        /* 2304 */
#define DIMF  (4*DIM)        /* 3072 */
#define LNEPS 1e-5f

typedef __attribute__((ext_vector_type(8)))  short short8;
typedef __attribute__((ext_vector_type(4)))  float floatx4;
typedef __attribute__((ext_vector_type(16))) float floatx16;
using bf16 = __hip_bfloat16;
typedef unsigned int u32;

static __device__ __forceinline__ bf16 f2bf(float v){ return __float2bfloat16(v); }
static __device__ __forceinline__ float bf2f(unsigned short u){
    union { unsigned int i; float f; } c; c.i = ((unsigned int)u) << 16; return c.f;
}
static __device__ __forceinline__ unsigned short bfu(float v){ return __bfloat16_as_ushort(f2bf(v)); }
static __device__ __forceinline__ u32 pk2(float a, float b){
    return (u32)bfu(a) | ((u32)bfu(b) << 16);
}

// async global->LDS, 16B per lane
static __device__ __forceinline__ void gl_lds16(const void* g, void* l) {
    __builtin_amdgcn_global_load_lds((const __attribute__((address_space(1))) void*)g,
                                     (__attribute__((address_space(3))) void*)l, 16, 0, 0);
}

// ---------------------------------------------------------------------------
// W [L][K][N] fp32  ->  WT [L][N][K] bf16   (tiled transpose via LDS)
// ---------------------------------------------------------------------------
__global__ void k_transpose_convert(const float* __restrict__ W, bf16* __restrict__ WT,
                                    int K, int N) {
    __shared__ float tile[32][33];
    int l = blockIdx.z;
    const float* Wl = W + (size_t)l * K * N;
    bf16* WTl = WT + (size_t)l * K * N;
    int n0 = blockIdx.x * 32, k0 = blockIdx.y * 32;
    int tx = threadIdx.x, ty = threadIdx.y;
#pragma unroll
    for (int i = 0; i < 4; i++)
        tile[ty + i*8][tx] = Wl[(size_t)(k0 + ty + i*8) * N + n0 + tx];
    __syncthreads();
#pragma unroll
    for (int i = 0; i < 4; i++)
        WTl[(size_t)(n0 + ty + i*8) * K + k0 + tx] = f2bf(tile[tx][ty + i*8]);
}

// ---------------------------------------------------------------------------
// LayerNorm: x fp32 [ROWS][DIM] -> y bf16.  One wave per row, float4 loads.
// ---------------------------------------------------------------------------
__global__ __launch_bounds__(256) void k_layernorm(const float* __restrict__ x,
                                                   const float* __restrict__ g,
                                                   const float* __restrict__ b,
                                                   bf16* __restrict__ y) {
    int row  = blockIdx.x * 4 + (threadIdx.x >> 6);
    int lane = threadIdx.x & 63;
    const float4* xr = (const float4*)(x + (size_t)row * DIM);
    float4 v[3];
    float s = 0.f, s2 = 0.f;
#pragma unroll
    for (int i = 0; i < 3; i++) {
        v[i] = xr[lane + i*64];
        s  += v[i].x + v[i].y + v[i].z + v[i].w;
        s2 += v[i].x*v[i].x + v[i].y*v[i].y + v[i].z*v[i].z + v[i].w*v[i].w;
    }
#pragma unroll
    for (int m = 1; m < 64; m <<= 1) { s += __shfl_xor(s, m); s2 += __shfl_xor(s2, m); }
    float mu  = s * (1.f / DIM);
    float var = s2 * (1.f / DIM) - mu * mu;
    float rs  = rsqrtf(var + LNEPS);
    bf16* yr = y + (size_t)row * DIM;
    const float4* g4 = (const float4*)g;
    const float4* b4 = (const float4*)b;
#pragma unroll
    for (int i = 0; i < 3; i++) {
        float4 gg = g4[lane + i*64], bb = b4[lane + i*64];
        float r0 = (v[i].x - mu) * rs * gg.x + bb.x;
        float r1 = (v[i].y - mu) * rs * gg.y + bb.y;
        float r2 = (v[i].z - mu) * rs * gg.z + bb.z;
        float r3 = (v[i].w - mu) * rs * gg.w + bb.w;
        uint2 u; u.x = pk2(r0, r1); u.y = pk2(r2, r3);
        *(uint2*)&yr[4 * (lane + i*64)] = u;
    }
}

// ---------------------------------------------------------------------------
// 2-phase double-buffered GEMM: STAGE(next) -> compute(cur) -> vmcnt(0)+barrier.
// BM=BN=128, BK=32, 4 waves 2x2, gl_lds width-16, XCD swizzle.
// MODE 0: bf16 store; MODE 1: bf16 fast-GELU store; MODE 2: fp32 residual add.
// ---------------------------------------------------------------------------
template<int MODE>
__global__ __launch_bounds__(256) void k_gemm(const bf16* __restrict__ A,
                                              const bf16* __restrict__ WT,
                                              const float* __restrict__ bias,
                                              bf16* __restrict__ outb,
                                              float* __restrict__ outf,
                                              int N, int K) {
    __shared__ __align__(16) bf16 As[2][128*32];
    __shared__ __align__(16) bf16 Bs[2][128*32];
    int nt = N >> 7;
    int nwg = gridDim.x;
    int fblk = blockIdx.x;
    int swz = (fblk & 7) * (nwg >> 3) + (fblk >> 3);  // XCD-chunked, bijective
    int m0 = (swz / nt) * 128, n0 = (swz % nt) * 128;
    int t = threadIdx.x;
    int lane = t & 63, w = t >> 6;
    int wr = (w >> 1) * 64, wc = (w & 1) * 64;
    int lr = lane & 15, lg = lane >> 4;
    int c0 = t, c1 = 256 + t;
    int r0g = c0 >> 2, e0 = (c0 & 3) * 8;
    int r1g = c1 >> 2, e1 = (c1 & 3) * 8;
    const bf16* Arow0 = A  + (size_t)(m0 + r0g) * K + e0;
    const bf16* Arow1 = A  + (size_t)(m0 + r1g) * K + e1;
    const bf16* Brow0 = WT + (size_t)(n0 + r0g) * K + e0;
    const bf16* Brow1 = WT + (size_t)(n0 + r1g) * K + e1;

    floatx4 acc[4][4] = {};
    int NT = K >> 5;
    gl_lds16(Arow0, &As[0][c0 * 8]);
    gl_lds16(Brow0, &Bs[0][c0 * 8]);
    gl_lds16(Arow1, &As[0][c1 * 8]);
    gl_lds16(Brow1, &Bs[0][c1 * 8]);
    __syncthreads();
    int cur = 0;
    for (int ks = 0; ks < NT; ks++) {
        if (ks + 1 < NT) {
            int ko = (ks + 1) << 5;
            gl_lds16(Arow0 + ko, &As[cur^1][c0 * 8]);
            gl_lds16(Brow0 + ko, &Bs[cur^1][c0 * 8]);
            gl_lds16(Arow1 + ko, &As[cur^1][c1 * 8]);
            gl_lds16(Brow1 + ko, &Bs[cur^1][c1 * 8]);
        }
        short8 af[4], bfr[4];
#pragma unroll
        for (int i = 0; i < 4; i++) af[i]  = *(const short8*)&As[cur][(wr + i*16 + lr)*32 + lg*8];
#pragma unroll
        for (int j = 0; j < 4; j++) bfr[j] = *(const short8*)&Bs[cur][(wc + j*16 + lr)*32 + lg*8];
#pragma unroll
        for (int i = 0; i < 4; i++)
#pragma unroll
            for (int j = 0; j < 4; j++)
                acc[i][j] = __builtin_amdgcn_mfma_f32_16x16x32_bf16(af[i], bfr[j], acc[i][j], 0, 0, 0);
        __syncthreads();
        cur ^= 1;
    }
#pragma unroll
    for (int i = 0; i < 4; i++)
#pragma unroll
        for (int j = 0; j < 4; j++)
#pragma unroll
            for (int r = 0; r < 4; r++) {
                int row = m0 + wr + i*16 + lg*4 + r;
                int col = n0 + wc + j*16 + lr;
                float vv = acc[i][j][r] + bias[col];
                if (MODE == 0) {
                    outb[(size_t)row * N + col] = f2bf(vv);
                } else if (MODE == 1) {
                    float u = 1.5957691216f * (vv + 0.044715f * vv * vv * vv);
                    float gs = 1.f / (1.f + __expf(-u));
                    outb[(size_t)row * N + col] = f2bf(vv * gs);
                } else {
                    outf[(size_t)row * N + col] += vv;
                }
            }
}

// ---------------------------------------------------------------------------
// Flash attention, swapped 32x32 QK^T, in-lane softmax, fused residual add.
// QBLK=128 (4 waves x 32 q-rows), KVBLK=64, grid 768: XCD = batch.
// S^T = mfma(A=K, B=Q): lane q=lane&31, hi=lane>>5 holds P[q][k],
//   k = (r&3)+8*(r>>2)+4*hi (+32*kb).  Row max/sum in-lane + shfl_xor(32).
// P -> LDS as packed b64 writes into XOR-swizzled [32][64] per-wave tile;
// PV reads b128 A-frags from same tile (unit u = 2ks+hi <-> u = m+4kb).
// K LDS: XOR-swizzled [64][64] (u ^= row&7) -> floor-rate b128 reads.
// V^T LDS: dword-XOR swizzle (as R3/R4).
// ---------------------------------------------------------------------------
static __device__ __forceinline__ int vt_off(int d, int k) {
    int dw = d * 36 + (k >> 1);
    dw ^= (d & 0x38) >> 1;
    return dw * 2 + (k & 1);
}

__global__ __launch_bounds__(256, 3) void k_attn(const bf16* __restrict__ qkv,
                                                 float* __restrict__ x) {
    int f = blockIdx.x;           // 768 blocks; XCD = f % 8
    int b  = f & 7;
    int rr = f >> 3;
    int h  = rr % 12;
    int qt = rr / 12;
    int t = threadIdx.x, lane = t & 63, w = t >> 6;
    int q = lane & 31, hi = lane >> 5;
    const size_t bn0 = (size_t)b * NCTX;
    const bf16* Qg = qkv + bn0 * DIM3 + h * DH;
    const bf16* Kg = Qg + DIM;
    const bf16* Vg = Qg + 2 * DIM;
    int q0 = qt * 128 + w * 32;

    const float qs = 0.036084391824351615f * 1.4426950408889634f;  // 768^-0.5 * log2e
    // Q fragments (B operand): qf[s] = Q[q0+q][16s+8hi+0..7] * qs
    short8 qf[4];
#pragma unroll
    for (int s = 0; s < 4; s++) {
        short8 raw = *(const short8*)&Qg[(size_t)(q0 + q) * DIM3 + s*16 + hi*8];
        short8 o;
#pragma unroll
        for (int e = 0; e < 8; e++)
            o[e] = (short)bfu(bf2f((unsigned short)raw[e]) * qs);
        qf[s] = o;
    }

    __shared__ __align__(16) bf16 KsS[64*64];     // XOR-swizzled [k][d]
    __shared__ __align__(16) bf16 VTs[64*72];     // vt_off-swizzled [d][k]
    __shared__ __align__(16) bf16 PsS[4][32*64];  // per-wave XOR-swizzled [q][k]
    __shared__ float wbc[4][32];                  // per-wave q-broadcast (corr / 1/l)

    u32* ksw = (u32*)KsS;
    u32* psw = (u32*)&PsS[w][0];

    // staging geometry: 2 chunks of 16B per thread, rows=k 0..63, col8 in d
    int sr[2], sc[2];
#pragma unroll
    for (int it = 0; it < 2; it++) { int c = it*256 + t; sr[it] = c >> 3; sc[it] = (c & 7) * 8; }

    floatx16 pacc[2] = {};
    float mrow = -3e38f, lrow = 0.f;

    uint4 kreg[2], vreg[2];
#pragma unroll
    for (int it = 0; it < 2; it++) {
        kreg[it] = *(const uint4*)&Kg[(size_t)sr[it] * DIM3 + sc[it]];
        vreg[it] = *(const uint4*)&Vg[(size_t)sr[it] * DIM3 + sc[it]];
    }

    for (int kt = 0; kt < 16; kt++) {
        __syncthreads();          // all waves done reading previous tile's LDS
#pragma unroll
        for (int it = 0; it < 2; it++) {
            int row = sr[it], u = sc[it] >> 3;
            *(uint4*)(ksw + row*32 + ((u ^ (row & 7)) << 2)) = kreg[it];
            const bf16* vp = (const bf16*)&vreg[it];
#pragma unroll
            for (int e = 0; e < 8; e++) VTs[vt_off(sc[it] + e, row)] = vp[e];
        }
        __syncthreads();
        if (kt + 1 < 16) {        // T14: next-tile loads fly under compute
            int kv0 = (kt + 1) * 64;
#pragma unroll
            for (int it = 0; it < 2; it++) {
                kreg[it] = *(const uint4*)&Kg[(size_t)(kv0 + sr[it]) * DIM3 + sc[it]];
                vreg[it] = *(const uint4*)&Vg[(size_t)(kv0 + sr[it]) * DIM3 + sc[it]];
            }
        }

        // ---- swapped QK^T: sacc[kb][r] = S[q][k=crow(r,hi)+32kb] (log2-domain)
        floatx16 sacc[2] = {};
#pragma unroll
        for (int kb = 0; kb < 2; kb++) {
#pragma unroll
            for (int s = 0; s < 4; s++) {
                int row = kb*32 + q;
                short8 kf = *(const short8*)(ksw + row*32 + (((2*s + hi) ^ (row & 7)) << 2));
                sacc[kb] = __builtin_amdgcn_mfma_f32_32x32x16_bf16(kf, qf[s], sacc[kb], 0, 0, 0);
            }
        }

        // ---- in-lane softmax over 32 values + cross-half combine
        float mx = sacc[0][0];
#pragma unroll
        for (int r = 1; r < 16; r++) mx = fmaxf(mx, sacc[0][r]);
#pragma unroll
        for (int r = 0; r < 16; r++) mx = fmaxf(mx, sacc[1][r]);
        mx = fmaxf(mx, __shfl_xor(mx, 32));
        bool chg = mx > mrow + 8.f;       // defer-max THR=8
        if (__any(chg)) {
            float mnew = chg ? mx : mrow;
            float corr = exp2f(mrow - mnew);
            mrow = mnew;
            lrow *= corr;
            wbc[w][q] = corr;             // both hi-halves write same value
#pragma unroll
            for (int r = 0; r < 16; r++) {
                float c = wbc[w][(r & 3) + 8*(r >> 2) + 4*hi];
                pacc[0][r] *= c; pacc[1][r] *= c;
            }
        }
        float sum = 0.f;
#pragma unroll
        for (int kb = 0; kb < 2; kb++) {
#pragma unroll
            for (int m = 0; m < 4; m++) {
                float p0 = exp2f(sacc[kb][4*m+0] - mrow);
                float p1 = exp2f(sacc[kb][4*m+1] - mrow);
                float p2 = exp2f(sacc[kb][4*m+2] - mrow);
                float p3 = exp2f(sacc[kb][4*m+3] - mrow);
                sum += (p0 + p1) + (p2 + p3);
                uint2 d2; d2.x = pk2(p0, p1); d2.y = pk2(p2, p3);
                *(uint2*)(psw + q*32 + (((m + 4*kb) ^ (q & 7)) << 2) + 2*hi) = d2;
            }
        }
        sum += __shfl_xor(sum, 32);
        lrow += sum;

        // ---- PV: O[q][d] += P[q][k] V[k][d], d-blocks 0/1, k-steps 0..3
#pragma unroll
        for (int ks = 0; ks < 4; ks++) {
            short8 pa = *(const short8*)(psw + q*32 + (((2*ks + hi) ^ (q & 7)) << 2));
#pragma unroll
            for (int db = 0; db < 2; db++) {
                short8 vb = *(const short8*)&VTs[vt_off(db*32 + q, 16*ks + 8*hi)];
                pacc[db] = __builtin_amdgcn_mfma_f32_32x32x16_bf16(pa, vb, pacc[db], 0, 0, 0);
            }
        }
    }

    // ---- epilogue: O[q][d]/l  +=  into x
    wbc[w][q] = 1.f / lrow;
    float* xr = x + bn0 * DIM + (size_t)h * DH;
#pragma unroll
    for (int r = 0; r < 16; r++) {
        int qrow = (r & 3) + 8*(r >> 2) + 4*hi;
        float li = wbc[w][qrow];
#pragma unroll
        for (int db = 0; db < 2; db++) {
            int col = db*32 + q;
            xr[(size_t)(q0 + qrow) * DIM + col] += pacc[db][r] * li;
        }
    }
}

// ---------------------------------------------------------------------------
extern "C" void kernel_launch(void* const* d_in, const int* in_sizes, int n_in,
                              void* d_out, int out_size, void* d_ws, size_t ws_size,
                              hipStream_t stream) {
    const float* x_in  = (const float*)d_in[0];
    const float* ln1_g = (const float*)d_in[1];
    const float* ln1_b = (const float*)d_in[2];
    const float* wqkv  = (const float*)d_in[3];
    const float* bqkv  = (const float*)d_in[4];
    const float* ln2_g = (const float*)d_in[5];
    const float* ln2_b = (const float*)d_in[6];
    const float* w1    = (const float*)d_in[7];
    const float* b1    = (const float*)d_in[8];
    const float* w2    = (const float*)d_in[9];
    const float* b2    = (const float*)d_in[10];
    float* x = (float*)d_out;

    char* ws = (char*)d_ws;
    size_t off = 0;
    auto alloc = [&](size_t bytes) { void* p = ws + off; off += (bytes + 255) & ~255ull; return p; };
    bf16* wqkvT = (bf16*)alloc((size_t)DEPTH * DIM * DIM3 * 2);
    bf16* w1T   = (bf16*)alloc((size_t)DEPTH * DIM * DIMF * 2);
    bf16* w2T   = (bf16*)alloc((size_t)DEPTH * DIMF * DIM * 2);
    bf16* xn    = (bf16*)alloc((size_t)ROWS * DIM * 2);
    bf16* qkvh  = (bf16*)alloc((size_t)ROWS * DIMF * 2);
    if (off > ws_size) return;

    hipMemcpyAsync(x, x_in, (size_t)ROWS * DIM * 4, hipMemcpyDeviceToDevice, stream);

    k_transpose_convert<<<dim3(DIM3/32, DIM/32,  DEPTH), dim3(32, 8), 0, stream>>>(wqkv, wqkvT, DIM,  DIM3);
    k_transpose_convert<<<dim3(DIMF/32, DIM/32,  DEPTH), dim3(32, 8), 0, stream>>>(w1,   w1T,   DIM,  DIMF);
    k_transpose_convert<<<dim3(DIM/32,  DIMF/32, DEPTH), dim3(32, 8), 0, stream>>>(w2,   w2T,   DIMF, DIM);

    for (int l = 0; l < DEPTH; l++) {
        k_layernorm<<<ROWS/4, 256, 0, stream>>>(x, ln1_g + l*DIM, ln1_b + l*DIM, xn);
        k_gemm<0><<<dim3((DIM3/128)*(ROWS/128)), 256, 0, stream>>>(
            xn, wqkvT + (size_t)l*DIM*DIM3, bqkv + (size_t)l*DIM3, qkvh, nullptr, DIM3, DIM);
        k_attn<<<dim3(768), 256, 0, stream>>>(qkvh, x);
        k_layernorm<<<ROWS/4, 256, 0, stream>>>(x, ln2_g + l*DIM, ln2_b + l*DIM, xn);
        k_gemm<1><<<dim3((DIMF/128)*(ROWS/128)), 256, 0, stream>>>(
            xn, w1T + (size_t)l*DIM*DIMF, b1 + (size_t)l*DIMF, qkvh, nullptr, DIMF, DIM);
        k_gemm<2><<<dim3((DIM/128)*(ROWS/128)), 256, 0, stream>>>(
            qkvh, w2T + (size_t)l*DIMF*DIM, b2 + (size_t)l*DIM, nullptr, x, DIM, DIMF);
    }
}